// Round 5
// baseline (12006.122 us; speedup 1.0000x reference)
//
#include <hip/hip_runtime.h>

typedef unsigned short u16;
typedef unsigned int   u32;
typedef unsigned long long u64;

#define LTC_B 32
#define LTC_L 1024
#define LTC_D 512
#define LTC_H 512
#define NG 8               // groups
#define NP 16              // producer WGs per group (each owns 32+32 W rows)
#define NBG 4              // batches per group

typedef _Float16 f16x8  __attribute__((ext_vector_type(8)));
typedef _Float16 f16x2t __attribute__((ext_vector_type(2)));
typedef float    f32x4  __attribute__((ext_vector_type(4)));

static __device__ __forceinline__ u32 packh(float a, float b) {
    f16x2t p; p[0] = (_Float16)a; p[1] = (_Float16)b;
    return __builtin_bit_cast(u32, p);
}
static __device__ __forceinline__ float unplo(u32 w) {
    return (float)__builtin_bit_cast(f16x2t, w)[0];
}
static __device__ __forceinline__ float unphi(u32 w) {
    return (float)__builtin_bit_cast(f16x2t, w)[1];
}
static __device__ __forceinline__ float sigm(float x) {
    return 1.f / (1.f + __expf(-x));
}
static __device__ __forceinline__ float tanh_f(float x) {
    float e = __expf(2.f * x);          // inf-safe: e=inf -> 1, e=0 -> -1
    return 1.f - 2.f / (e + 1.f);
}
static __device__ __forceinline__ f16x8 cvt8(const float* p) {
    const float4 a = *(const float4*)p;
    const float4 b = *(const float4*)(p + 4);
    f16x8 r;
    r[0] = (_Float16)a.x; r[1] = (_Float16)a.y; r[2] = (_Float16)a.z; r[3] = (_Float16)a.w;
    r[4] = (_Float16)b.x; r[5] = (_Float16)b.y; r[6] = (_Float16)b.z; r[7] = (_Float16)b.w;
    return r;
}
static __device__ __forceinline__ bool stamp4(u64 a, u64 b, u64 c, u64 d, u32 k) {
    return ((u32)(a >> 32) == k) & ((u32)(b >> 32) == k) &
           ((u32)(c >> 32) == k) & ((u32)(d >> 32) == k);
}

// ---------------------------------------------------------------------------
// C[M,512](f16) = A[M,512](f32) . W[:,:512]^T(f32, row stride ldb) + bias(f32)
// ---------------------------------------------------------------------------
__global__ __launch_bounds__(256) void gemm_a32_c16(
    const float* __restrict__ A, const float* __restrict__ W, int ldb,
    const float* __restrict__ bias, u16* __restrict__ C)
{
    const int wave = threadIdx.x >> 6;
    const int lane = threadIdx.x & 63;
    const int tile = blockIdx.x * 4 + wave;
    const int nt = tile & 7;
    const int mt = tile >> 3;
    const int r16 = lane & 15;
    const int kq  = (lane >> 4) * 8;

    const float* ap = A + (size_t)(mt * 64 + r16) * LTC_D + kq;
    const float* wp = W + (size_t)(nt * 64 + r16) * ldb + kq;

    f32x4 acc[4][4];
    #pragma unroll
    for (int i = 0; i < 4; ++i)
        #pragma unroll
        for (int jj = 0; jj < 4; ++jj) acc[i][jj] = (f32x4){0.f, 0.f, 0.f, 0.f};

    for (int ks = 0; ks < 16; ++ks) {
        f16x8 af[4], bf[4];
        #pragma unroll
        for (int t = 0; t < 4; ++t) {
            af[t] = cvt8(ap + (size_t)t * 16 * LTC_D + ks * 32);
            bf[t] = cvt8(wp + (size_t)t * 16 * ldb  + ks * 32);
        }
        #pragma unroll
        for (int mi = 0; mi < 4; ++mi)
            #pragma unroll
            for (int ni = 0; ni < 4; ++ni)
                acc[mi][ni] = __builtin_amdgcn_mfma_f32_16x16x32_f16(
                    af[mi], bf[ni], acc[mi][ni], 0, 0, 0);
    }
    const int row = (lane >> 4) * 4;   // C/D: col=lane&15 (n), row=(lane>>4)*4+reg (m)
    const int col = lane & 15;
    #pragma unroll
    for (int ni = 0; ni < 4; ++ni) {
        const int n = nt * 64 + ni * 16 + col;
        const float bv = bias[n];
        #pragma unroll
        for (int mi = 0; mi < 4; ++mi)
            #pragma unroll
            for (int r = 0; r < 4; ++r) {
                _Float16 h = (_Float16)(acc[mi][ni][r] + bv);
                C[(size_t)(mt * 64 + mi * 16 + row + r) * LTC_H + n] =
                    __builtin_bit_cast(u16, h);
            }
    }
}

// ---------------------------------------------------------------------------
// C[M,512](f32) = A[M,512](f16) . W^T(f32, row stride 512) + bias(f32)
// ---------------------------------------------------------------------------
__global__ __launch_bounds__(256) void gemm_a16_c32(
    const u16* __restrict__ A, const float* __restrict__ W,
    const float* __restrict__ bias, float* __restrict__ C)
{
    const int wave = threadIdx.x >> 6;
    const int lane = threadIdx.x & 63;
    const int tile = blockIdx.x * 4 + wave;
    const int nt = tile & 7;
    const int mt = tile >> 3;
    const int r16 = lane & 15;
    const int kq  = (lane >> 4) * 8;

    const _Float16* ap = (const _Float16*)A + (size_t)(mt * 64 + r16) * LTC_D + kq;
    const float*    wp = W + (size_t)(nt * 64 + r16) * LTC_H + kq;

    f32x4 acc[4][4];
    #pragma unroll
    for (int i = 0; i < 4; ++i)
        #pragma unroll
        for (int jj = 0; jj < 4; ++jj) acc[i][jj] = (f32x4){0.f, 0.f, 0.f, 0.f};

    for (int ks = 0; ks < 16; ++ks) {
        f16x8 af[4], bf[4];
        #pragma unroll
        for (int t = 0; t < 4; ++t) {
            af[t] = *(const f16x8*)(ap + (size_t)t * 16 * LTC_D + ks * 32);
            bf[t] = cvt8(wp + (size_t)t * 16 * LTC_H + ks * 32);
        }
        #pragma unroll
        for (int mi = 0; mi < 4; ++mi)
            #pragma unroll
            for (int ni = 0; ni < 4; ++ni)
                acc[mi][ni] = __builtin_amdgcn_mfma_f32_16x16x32_f16(
                    af[mi], bf[ni], acc[mi][ni], 0, 0, 0);
    }
    const int row = (lane >> 4) * 4;
    const int col = lane & 15;
    #pragma unroll
    for (int ni = 0; ni < 4; ++ni) {
        const int n = nt * 64 + ni * 16 + col;
        const float bv = bias[n];
        #pragma unroll
        for (int mi = 0; mi < 4; ++mi)
            #pragma unroll
            for (int r = 0; r < 4; ++r)
                C[(size_t)(mt * 64 + mi * 16 + row + r) * LTC_H + n] =
                    acc[mi][ni][r] + bv;
    }
}

// ---------------------------------------------------------------------------
// ODE scan: 8 groups x 4 batches, 16 producer WGs per group (128 WGs).
// Round-0 structure + own-column LDS shortcut (round 4, verified) + TWO
// detection-latency edits to the SAME validated channel (bytes unchanged):
// (a) sweep PRIMING: the first 4 poll loads issue right after the red[]
//     write, BEFORE barrier #1 and BEFORE the publish stores — so wave 0's
//     first stamp check no longer serializes behind its own store acks
//     (in-order vmcnt retire), and sampling starts earlier for all waves;
// (b) depth-2 pipelined spin: each iteration issues the next 4-load set
//     before stamp-checking the current one, halving the sampling period.
// Stale/early samples are rejected by the stamp check exactly as before.
// Remote exchange stays: stamped u64 (stamp<<32 | f16 pair), relaxed
// agent-scope publish, batched 4-load LLC sweep, bounded budget (protocol
// failure => wrong answer via absmax, never a hang).
// ---------------------------------------------------------------------------
__global__ __launch_bounds__(256) void ltc_scan(
    u32* __restrict__ drive,            // f16 pairs; rewritten with fwd
    const u32* __restrict__ gatex,      // f16 pairs
    const float* __restrict__ W_rec,
    const float* __restrict__ W_gate,
    const float* __restrict__ log_tau,
    u64* __restrict__ hbuf,             // [2 par][8 g][4 b][256] stamped pairs
    float* __restrict__ hlast)
{
    const int g   = blockIdx.x & 7;     // group
    const int p   = blockIdx.x >> 3;    // producer slice 0..15
    const int tid = threadIdx.x;
    const int lane = tid & 63;
    const int wv   = tid >> 6;          // n-tile: 0-1 rec rows, 2-3 gate rows

    __shared__ u32 hTu[16][260];        // h as f16 pairs; rows 0-3 = batches
    __shared__ float red[64][17];       // matvec results [n][m]

    // ---- one-time: B-fragments (my 32 W_rec + 32 Wg_h rows) into registers
    const int nl = wv * 16 + (lane & 15);      // 0..63
    const int kq = (lane >> 4) * 8;
    const float* wrow = (nl < 32)
        ? (W_rec  + (size_t)(32 * p + nl) * LTC_H)
        : (W_gate + (size_t)(32 * p + nl - 32) * (LTC_D + LTC_H) + LTC_D);
    f16x8 Wf[16];
    #pragma unroll
    for (int ks = 0; ks < 16; ++ks) Wf[ks] = cvt8(wrow + ks * 32 + kq);

    for (int i = tid; i < 16 * 260; i += 256) (&hTu[0][0])[i] = 0;  // h0 = 0
    __syncthreads();

    // ---- update-thread setup (wave 0 only: 4 b x 16 pairs = 64 threads)
    const int ub = tid >> 4;            // local batch (tid<64)
    const int jp = tid & 15;
    const int j0 = 32 * p + 2 * jp;
    const int gb = g * NBG + ub;        // global batch
    float h0 = 0.f, h1 = 0.f, stau0 = 0.f, stau1 = 0.f;
    size_t dwofs = 0;
    if (tid < 64) {
        stau0 = (1.f / 6.f) * __expf(-log_tau[j0]);
        stau1 = (1.f / 6.f) * __expf(-log_tau[j0 + 1]);
        dwofs = (size_t)gb * LTC_L * 256 + 16 * p + jp;
    }

    const _Float16* hrow = (const _Float16*)&hTu[lane & 15][0];
    u32 kp1 = 0;
    int budget = 1 << 22;               // global failing-poll budget (no hangs)
    const bool own = ((tid >> 4) == p); // my polled column is published by MY WG

    // prime l=0 inputs
    u32 dw = 0, gw = 0;
    if (tid < 64) { dw = drive[dwofs]; gw = gatex[dwofs]; }

    for (int l = 0; l < LTC_L; ++l) {
        const float d0 = unplo(dw), d1 = unphi(dw);
        const float gx0 = unplo(gw), gx1 = unphi(gw);
        // prefetch next step's inputs (overlaps with 6 sub-steps of work)
        u32 dn = 0, gn = 0;
        if (tid < 64 && l + 1 < LTC_L) {
            dn = drive[dwofs + (size_t)(l + 1) * 256];
            gn = gatex[dwofs + (size_t)(l + 1) * 256];
        }
        #pragma unroll 1
        for (int s = 0; s < 6; ++s) {
            // ---- matvec: red[n][m] = sum_k h[m,k] * Wrow(n)[k] (2 acc chains)
            f32x4 acc0 = (f32x4){0.f, 0.f, 0.f, 0.f}, acc1 = acc0;
            #pragma unroll
            for (int ks = 0; ks < 16; ks += 2) {
                const f16x8 a0 = *(const f16x8*)(hrow + ks * 32 + kq);
                const f16x8 a1 = *(const f16x8*)(hrow + (ks + 1) * 32 + kq);
                acc0 = __builtin_amdgcn_mfma_f32_16x16x32_f16(a0, Wf[ks],     acc0, 0, 0, 0);
                acc1 = __builtin_amdgcn_mfma_f32_16x16x32_f16(a1, Wf[ks + 1], acc1, 0, 0, 0);
            }
            {
                const int n  = wv * 16 + (lane & 15);
                const int rb = (lane >> 4) * 4;
                #pragma unroll
                for (int r = 0; r < 4; ++r) red[n][rb + r] = acc0[r] + acc1[r];
            }
            ++kp1;
            const size_t pbase = (size_t)((kp1 & 1u) * NG + g) * (NBG * 256);
            const u64* sb = hbuf + pbase + tid;
            // ---- sweep PRIMING: issue first poll set before barrier/publish.
            //      Early samples mostly carry stale stamps -> rejected below.
            u64 c0 = 0, c1 = 0, c2 = 0, c3 = 0;
            if (!own) {
                c0 = __hip_atomic_load(sb,       __ATOMIC_RELAXED,
                                       __HIP_MEMORY_SCOPE_AGENT);
                c1 = __hip_atomic_load(sb + 256, __ATOMIC_RELAXED,
                                       __HIP_MEMORY_SCOPE_AGENT);
                c2 = __hip_atomic_load(sb + 512, __ATOMIC_RELAXED,
                                       __HIP_MEMORY_SCOPE_AGENT);
                c3 = __hip_atomic_load(sb + 768, __ATOMIC_RELAXED,
                                       __HIP_MEMORY_SCOPE_AGENT);
            }
            __syncthreads();
            // ---- update + own-column LDS write + single LLC publish --------
            if (tid < 64) {
                const float rec0 = red[2 * jp][ub],     gh0 = red[32 + 2 * jp][ub];
                const float rec1 = red[2 * jp + 1][ub], gh1 = red[32 + 2 * jp + 1][ub];
                h0 += stau0 * (sigm(gx0 + gh0) * tanh_f(d0 + rec0) - h0);
                h1 += stau1 * (sigm(gx1 + gh1) * tanh_f(d1 + rec1) - h1);
                const u32 pr = packh(h0, h1);
                hTu[ub][16 * p + jp] = pr;      // own column: LDS shortcut
                const u64 v = ((u64)kp1 << 32) | (u64)pr;
                __hip_atomic_store(hbuf + pbase + (size_t)ub * 256 + 16 * p + jp,
                                   v, __ATOMIC_RELAXED, __HIP_MEMORY_SCOPE_AGENT);
            }
            // ---- gather: remote columns, depth-2 pipelined LLC sweep -------
            if (!own) {
                bool ok;
                do {
                    u64 n0 = __hip_atomic_load(sb,       __ATOMIC_RELAXED,
                                               __HIP_MEMORY_SCOPE_AGENT);
                    u64 n1 = __hip_atomic_load(sb + 256, __ATOMIC_RELAXED,
                                               __HIP_MEMORY_SCOPE_AGENT);
                    u64 n2 = __hip_atomic_load(sb + 512, __ATOMIC_RELAXED,
                                               __HIP_MEMORY_SCOPE_AGENT);
                    u64 n3 = __hip_atomic_load(sb + 768, __ATOMIC_RELAXED,
                                               __HIP_MEMORY_SCOPE_AGENT);
                    ok = stamp4(c0, c1, c2, c3, kp1);   // waits c*, leaves n* in flight
                    if (!ok) { c0 = n0; c1 = n1; c2 = n2; c3 = n3; }
                } while (!ok && --budget > 0);
                hTu[0][tid] = (u32)c0; hTu[1][tid] = (u32)c1;
                hTu[2][tid] = (u32)c2; hTu[3][tid] = (u32)c3;
            }
            __syncthreads();
        }
        if (tid < 64) drive[dwofs + (size_t)l * 256] = packh(h0, h1);  // fwd
        dw = dn; gw = gn;
    }
    if (tid < 64) {
        hlast[(size_t)gb * LTC_H + j0]     = h0;
        hlast[(size_t)gb * LTC_H + j0 + 1] = h1;
    }
}

// ---------------------------------------------------------------------------
extern "C" void kernel_launch(void* const* d_in, const int* in_sizes, int n_in,
                              void* d_out, int out_size, void* d_ws, size_t ws_size,
                              hipStream_t stream)
{
    const float* x       = (const float*)d_in[0];
    const float* log_tau = (const float*)d_in[1];
    const float* W_in    = (const float*)d_in[2];
    const float* b_in    = (const float*)d_in[3];
    const float* W_rec   = (const float*)d_in[4];
    const float* W_gate  = (const float*)d_in[5];
    const float* b_gate  = (const float*)d_in[6];
    const float* W_out   = (const float*)d_in[7];
    const float* b_out   = (const float*)d_in[8];

    float* out   = (float*)d_out;                       // (32,1024,512) fp32
    float* hlast = out + (size_t)LTC_B * LTC_L * LTC_H; // (32,512) fp32

    u32* ws    = (u32*)d_ws;                   // 64 MB + 128 KB used
    u32* drive = ws;                           // 8388608 u32 (f16 pairs)
    u32* gatex = ws + 8388608;                 // 8388608 u32
    u64* hbuf  = (u64*)(ws + 16777216);        // 16384 u64 stamped pairs

    const int blocks = (LTC_B * LTC_L / 64) * (LTC_H / 64) / 4;   // 1024

    gemm_a32_c16<<<blocks, 256, 0, stream>>>(x, W_in, LTC_D, b_in, (u16*)drive);
    gemm_a32_c16<<<blocks, 256, 0, stream>>>(x, W_gate, LTC_D + LTC_H, b_gate, (u16*)gatex);
    ltc_scan<<<NG * NP, 256, 0, stream>>>(drive, gatex, W_rec, W_gate, log_tau,
                                          hbuf, hlast);
    gemm_a16_c32<<<blocks, 256, 0, stream>>>((const u16*)drive, W_out, b_out, out);
}

// Round 6
// 10387.653 us; speedup vs baseline: 1.1558x; 1.1558x over previous
//
#include <hip/hip_runtime.h>

typedef unsigned short u16;
typedef unsigned int   u32;
typedef unsigned long long u64;

#define LTC_B 32
#define LTC_L 1024
#define LTC_D 512
#define LTC_H 512
#define NG 8               // groups
#define NP 16              // producer WGs per group (each owns 32+32 W rows)
#define NBG 4              // batches per group

typedef _Float16 f16x8  __attribute__((ext_vector_type(8)));
typedef _Float16 f16x2t __attribute__((ext_vector_type(2)));
typedef float    f32x4  __attribute__((ext_vector_type(4)));

static __device__ __forceinline__ u32 packh(float a, float b) {
    f16x2t p; p[0] = (_Float16)a; p[1] = (_Float16)b;
    return __builtin_bit_cast(u32, p);
}
static __device__ __forceinline__ float unplo(u32 w) {
    return (float)__builtin_bit_cast(f16x2t, w)[0];
}
static __device__ __forceinline__ float unphi(u32 w) {
    return (float)__builtin_bit_cast(f16x2t, w)[1];
}
static __device__ __forceinline__ float sigm(float x) {
    return 1.f / (1.f + __expf(-x));
}
static __device__ __forceinline__ float tanh_f(float x) {
    float e = __expf(2.f * x);          // inf-safe: e=inf -> 1, e=0 -> -1
    return 1.f - 2.f / (e + 1.f);
}
static __device__ __forceinline__ f16x8 cvt8(const float* p) {
    const float4 a = *(const float4*)p;
    const float4 b = *(const float4*)(p + 4);
    f16x8 r;
    r[0] = (_Float16)a.x; r[1] = (_Float16)a.y; r[2] = (_Float16)a.z; r[3] = (_Float16)a.w;
    r[4] = (_Float16)b.x; r[5] = (_Float16)b.y; r[6] = (_Float16)b.z; r[7] = (_Float16)b.w;
    return r;
}
static __device__ __forceinline__ bool stamp2(u64 a, u64 b, u32 k) {
    return ((u32)(a >> 32) == k) & ((u32)(b >> 32) == k);
}

// ---------------------------------------------------------------------------
// C[M,512](f16) = A[M,512](f32) . W[:,:512]^T(f32, row stride ldb) + bias(f32)
// ---------------------------------------------------------------------------
__global__ __launch_bounds__(256) void gemm_a32_c16(
    const float* __restrict__ A, const float* __restrict__ W, int ldb,
    const float* __restrict__ bias, u16* __restrict__ C)
{
    const int wave = threadIdx.x >> 6;
    const int lane = threadIdx.x & 63;
    const int tile = blockIdx.x * 4 + wave;
    const int nt = tile & 7;
    const int mt = tile >> 3;
    const int r16 = lane & 15;
    const int kq  = (lane >> 4) * 8;

    const float* ap = A + (size_t)(mt * 64 + r16) * LTC_D + kq;
    const float* wp = W + (size_t)(nt * 64 + r16) * ldb + kq;

    f32x4 acc[4][4];
    #pragma unroll
    for (int i = 0; i < 4; ++i)
        #pragma unroll
        for (int jj = 0; jj < 4; ++jj) acc[i][jj] = (f32x4){0.f, 0.f, 0.f, 0.f};

    for (int ks = 0; ks < 16; ++ks) {
        f16x8 af[4], bf[4];
        #pragma unroll
        for (int t = 0; t < 4; ++t) {
            af[t] = cvt8(ap + (size_t)t * 16 * LTC_D + ks * 32);
            bf[t] = cvt8(wp + (size_t)t * 16 * ldb  + ks * 32);
        }
        #pragma unroll
        for (int mi = 0; mi < 4; ++mi)
            #pragma unroll
            for (int ni = 0; ni < 4; ++ni)
                acc[mi][ni] = __builtin_amdgcn_mfma_f32_16x16x32_f16(
                    af[mi], bf[ni], acc[mi][ni], 0, 0, 0);
    }
    const int row = (lane >> 4) * 4;   // C/D: col=lane&15 (n), row=(lane>>4)*4+reg (m)
    const int col = lane & 15;
    #pragma unroll
    for (int ni = 0; ni < 4; ++ni) {
        const int n = nt * 64 + ni * 16 + col;
        const float bv = bias[n];
        #pragma unroll
        for (int mi = 0; mi < 4; ++mi)
            #pragma unroll
            for (int r = 0; r < 4; ++r) {
                _Float16 h = (_Float16)(acc[mi][ni][r] + bv);
                C[(size_t)(mt * 64 + mi * 16 + row + r) * LTC_H + n] =
                    __builtin_bit_cast(u16, h);
            }
    }
}

// ---------------------------------------------------------------------------
// C[M,512](f32) = A[M,512](f16) . W^T(f32, row stride 512) + bias(f32)
// ---------------------------------------------------------------------------
__global__ __launch_bounds__(256) void gemm_a16_c32(
    const u16* __restrict__ A, const float* __restrict__ W,
    const float* __restrict__ bias, float* __restrict__ C)
{
    const int wave = threadIdx.x >> 6;
    const int lane = threadIdx.x & 63;
    const int tile = blockIdx.x * 4 + wave;
    const int nt = tile & 7;
    const int mt = tile >> 3;
    const int r16 = lane & 15;
    const int kq  = (lane >> 4) * 8;

    const _Float16* ap = (const _Float16*)A + (size_t)(mt * 64 + r16) * LTC_D + kq;
    const float*    wp = W + (size_t)(nt * 64 + r16) * LTC_H + kq;

    f32x4 acc[4][4];
    #pragma unroll
    for (int i = 0; i < 4; ++i)
        #pragma unroll
        for (int jj = 0; jj < 4; ++jj) acc[i][jj] = (f32x4){0.f, 0.f, 0.f, 0.f};

    for (int ks = 0; ks < 16; ++ks) {
        f16x8 af[4], bf[4];
        #pragma unroll
        for (int t = 0; t < 4; ++t) {
            af[t] = *(const f16x8*)(ap + (size_t)t * 16 * LTC_D + ks * 32);
            bf[t] = cvt8(wp + (size_t)t * 16 * LTC_H + ks * 32);
        }
        #pragma unroll
        for (int mi = 0; mi < 4; ++mi)
            #pragma unroll
            for (int ni = 0; ni < 4; ++ni)
                acc[mi][ni] = __builtin_amdgcn_mfma_f32_16x16x32_f16(
                    af[mi], bf[ni], acc[mi][ni], 0, 0, 0);
    }
    const int row = (lane >> 4) * 4;
    const int col = lane & 15;
    #pragma unroll
    for (int ni = 0; ni < 4; ++ni) {
        const int n = nt * 64 + ni * 16 + col;
        const float bv = bias[n];
        #pragma unroll
        for (int mi = 0; mi < 4; ++mi)
            #pragma unroll
            for (int r = 0; r < 4; ++r)
                C[(size_t)(mt * 64 + mi * 16 + row + r) * LTC_H + n] =
                    acc[mi][ni][r] + bv;
    }
}

// ---------------------------------------------------------------------------
// ODE scan: 8 groups x 4 batches, 16 producer WGs per group (128 WGs).
// BATCH-STREAM PIPELINE: the 4 batches split into stream X (batches 0-1,
// hTu rows 0-1, hbuf rows 0-1) and stream Y (batches 2-3, rows 2-3) whose
// phases are offset inside each sub-step so exchange latency hides under
// the other stream's MFMA pass. All loads are issued AND consumed within
// one barrier interval (round-5 lesson: __syncthreads drains vmcnt(0) —
// nothing survives a barrier).
//   phase A: issue gather_Y[k] (published last iter's phase C, ~1+ phase
//            old -> first check passes) | matvec_X(h_X[k]) -> red2[0]
//            | check Y -> hTu rows 2-3 | barrier
//   phase B: update_X -> publish X[k+1] (+ own-col LDS shortcut)
//            | matvec_Y(h_Y[k]) -> red2[1] (hides X store-ack drain)
//            | barrier
//   phase C: issue gather_X[k+1] (published at B start, ~600cyc old; loads
//            precede publish_Y stores so in-order vmcnt never waits acks)
//            | update_Y -> publish Y[k+1] | check X -> hTu rows 0-1 | barrier
// Exchange channel = the VALIDATED one, bytes unchanged: stamped u64
// (stamp<<32 | f16 pair), relaxed agent-scope atomics, bounded spin budget
// (protocol failure => wrong answer via absmax, never a hang). Parity
// safety (stamp t+2 overwrite vs stamp-t readers) holds by the same
// transitive argument: publishing t+2 requires having checked ALL t+1
// stamps, which requires every WG to have passed the phase that finished
// reading t. MFMA garbage rows (the other stream's rows mid-update) feed
// only unread red2 entries. Prologue publishes stamp-0 zeros (stale
// prior-run stamps != 0 are rejected by the check).
// ---------------------------------------------------------------------------
__global__ __launch_bounds__(256) void ltc_scan(
    u32* __restrict__ drive,            // f16 pairs; rewritten with fwd
    const u32* __restrict__ gatex,      // f16 pairs
    const float* __restrict__ W_rec,
    const float* __restrict__ W_gate,
    const float* __restrict__ log_tau,
    u64* __restrict__ hbuf,             // [2 par][8 g][4 b][256] stamped pairs
    float* __restrict__ hlast)
{
    const int g   = blockIdx.x & 7;     // group
    const int p   = blockIdx.x >> 3;    // producer slice 0..15
    const int tid = threadIdx.x;
    const int lane = tid & 63;
    const int wv   = tid >> 6;          // n-tile: 0-1 rec rows, 2-3 gate rows

    __shared__ u32 hTu[16][260];        // h pairs; rows 0-1 = X, 2-3 = Y
    __shared__ float red2[2][64][17];   // [0]=X matvec results, [1]=Y

    // ---- one-time: B-fragments (my 32 W_rec + 32 Wg_h rows) into registers
    const int nl = wv * 16 + (lane & 15);      // 0..63
    const int kq = (lane >> 4) * 8;
    const float* wrow = (nl < 32)
        ? (W_rec  + (size_t)(32 * p + nl) * LTC_H)
        : (W_gate + (size_t)(32 * p + nl - 32) * (LTC_D + LTC_H) + LTC_D);
    f16x8 Wf[16];
    #pragma unroll
    for (int ks = 0; ks < 16; ++ks) Wf[ks] = cvt8(wrow + ks * 32 + kq);

    for (int i = tid; i < 16 * 260; i += 256) (&hTu[0][0])[i] = 0;  // h0 = 0

    // ---- update-thread setup (tid<64: 4 b x 16 pairs; tid<32 = stream X)
    const int ub = tid >> 4;            // local batch (tid<64)
    const int jp = tid & 15;
    const int j0 = 32 * p + 2 * jp;
    const int gb = g * NBG + ub;        // global batch
    float h0 = 0.f, h1 = 0.f, stau0 = 0.f, stau1 = 0.f;
    size_t dwofs = 0;
    if (tid < 64) {
        stau0 = (1.f / 6.f) * __expf(-log_tau[j0]);
        stau1 = (1.f / 6.f) * __expf(-log_tau[j0 + 1]);
        dwofs = (size_t)gb * LTC_L * 256 + 16 * p + jp;
        // prologue: publish initial h=0 with stamp 0 into parity 0
        __hip_atomic_store(hbuf + (size_t)g * (NBG * 256) + (size_t)ub * 256
                               + 16 * p + jp,
                           0ull, __ATOMIC_RELAXED, __HIP_MEMORY_SCOPE_AGENT);
    }
    __syncthreads();

    const _Float16* hrow = (const _Float16*)&hTu[lane & 15][0];
    const int redn = wv * 16 + (lane & 15);
    const int redb = (lane >> 4) * 4;
    u32 kp1 = 0;                        // stamp of current (gathered) state
    int budget = 1 << 22;               // global failing-poll budget (no hangs)
    const bool own = ((tid >> 4) == p); // my polled column is published by MY WG

    // prime l=0 inputs
    u32 dw = 0, gw = 0;
    if (tid < 64) { dw = drive[dwofs]; gw = gatex[dwofs]; }

    for (int l = 0; l < LTC_L; ++l) {
        const float d0 = unplo(dw), d1 = unphi(dw);
        const float gx0 = unplo(gw), gx1 = unphi(gw);
        // prefetch next step's inputs (drains at next phase-A barrier)
        u32 dn = 0, gn = 0;
        if (tid < 64 && l + 1 < LTC_L) {
            dn = drive[dwofs + (size_t)(l + 1) * 256];
            gn = gatex[dwofs + (size_t)(l + 1) * 256];
        }
        #pragma unroll 1
        for (int s = 0; s < 6; ++s) {
            const u32 kold = kp1, knew = kp1 + 1;
            const size_t pbOld = (size_t)((kold & 1u) * NG + g) * (NBG * 256);
            const size_t pbNew = (size_t)((knew & 1u) * NG + g) * (NBG * 256);
            const u64* sbO = hbuf + pbOld + tid;
            const u64* sbN = hbuf + pbNew + tid;

            // ============ phase A ============
            u64 y0 = 0, y1 = 0;
            if (!own) {                 // issue gather_Y[kold] (old -> hits)
                y0 = __hip_atomic_load(sbO + 512, __ATOMIC_RELAXED,
                                       __HIP_MEMORY_SCOPE_AGENT);
                y1 = __hip_atomic_load(sbO + 768, __ATOMIC_RELAXED,
                                       __HIP_MEMORY_SCOPE_AGENT);
            }
            {   // matvec_X -> red2[0] (RTT of gather_Y hides under this)
                f32x4 acc0 = (f32x4){0.f, 0.f, 0.f, 0.f}, acc1 = acc0;
                #pragma unroll
                for (int ks = 0; ks < 16; ks += 2) {
                    const f16x8 a0 = *(const f16x8*)(hrow + ks * 32 + kq);
                    const f16x8 a1 = *(const f16x8*)(hrow + (ks + 1) * 32 + kq);
                    acc0 = __builtin_amdgcn_mfma_f32_16x16x32_f16(a0, Wf[ks],     acc0, 0, 0, 0);
                    acc1 = __builtin_amdgcn_mfma_f32_16x16x32_f16(a1, Wf[ks + 1], acc1, 0, 0, 0);
                }
                #pragma unroll
                for (int r = 0; r < 4; ++r) red2[0][redn][redb + r] = acc0[r] + acc1[r];
            }
            if (!own) {
                while (!stamp2(y0, y1, kold) && --budget > 0) {
                    y0 = __hip_atomic_load(sbO + 512, __ATOMIC_RELAXED,
                                           __HIP_MEMORY_SCOPE_AGENT);
                    y1 = __hip_atomic_load(sbO + 768, __ATOMIC_RELAXED,
                                           __HIP_MEMORY_SCOPE_AGENT);
                }
                hTu[2][tid] = (u32)y0;  // benign race vs matvec_X garbage rows
                hTu[3][tid] = (u32)y1;
            }
            __syncthreads();

            // ============ phase B ============
            if (tid < 32) {             // stream X update + publish
                const float rec0 = red2[0][2 * jp][ub],     gh0 = red2[0][32 + 2 * jp][ub];
                const float rec1 = red2[0][2 * jp + 1][ub], gh1 = red2[0][32 + 2 * jp + 1][ub];
                h0 += stau0 * (sigm(gx0 + gh0) * tanh_f(d0 + rec0) - h0);
                h1 += stau1 * (sigm(gx1 + gh1) * tanh_f(d1 + rec1) - h1);
                const u32 pr = packh(h0, h1);
                hTu[ub][16 * p + jp] = pr;          // own-col LDS shortcut
                __hip_atomic_store(hbuf + pbNew + (size_t)ub * 256 + 16 * p + jp,
                                   ((u64)knew << 32) | (u64)pr,
                                   __ATOMIC_RELAXED, __HIP_MEMORY_SCOPE_AGENT);
            }
            {   // matvec_Y -> red2[1] (X store-acks drain under this)
                f32x4 acc0 = (f32x4){0.f, 0.f, 0.f, 0.f}, acc1 = acc0;
                #pragma unroll
                for (int ks = 0; ks < 16; ks += 2) {
                    const f16x8 a0 = *(const f16x8*)(hrow + ks * 32 + kq);
                    const f16x8 a1 = *(const f16x8*)(hrow + (ks + 1) * 32 + kq);
                    acc0 = __builtin_amdgcn_mfma_f32_16x16x32_f16(a0, Wf[ks],     acc0, 0, 0, 0);
                    acc1 = __builtin_amdgcn_mfma_f32_16x16x32_f16(a1, Wf[ks + 1], acc1, 0, 0, 0);
                }
                #pragma unroll
                for (int r = 0; r < 4; ++r) red2[1][redn][redb + r] = acc0[r] + acc1[r];
            }
            __syncthreads();

            // ============ phase C ============
            u64 x0 = 0, x1 = 0;
            if (!own) {                 // issue gather_X[knew] FIRST (loads
                x0 = __hip_atomic_load(sbN,       __ATOMIC_RELAXED,   // older than
                                       __HIP_MEMORY_SCOPE_AGENT);     // publish_Y
                x1 = __hip_atomic_load(sbN + 256, __ATOMIC_RELAXED,   // stores)
                                       __HIP_MEMORY_SCOPE_AGENT);
            }
            if (tid >= 32 && tid < 64) {  // stream Y update + publish
                const float rec0 = red2[1][2 * jp][ub],     gh0 = red2[1][32 + 2 * jp][ub];
                const float rec1 = red2[1][2 * jp + 1][ub], gh1 = red2[1][32 + 2 * jp + 1][ub];
                h0 += stau0 * (sigm(gx0 + gh0) * tanh_f(d0 + rec0) - h0);
                h1 += stau1 * (sigm(gx1 + gh1) * tanh_f(d1 + rec1) - h1);
                const u32 pr = packh(h0, h1);
                hTu[ub][16 * p + jp] = pr;          // own-col LDS shortcut
                __hip_atomic_store(hbuf + pbNew + (size_t)ub * 256 + 16 * p + jp,
                                   ((u64)knew << 32) | (u64)pr,
                                   __ATOMIC_RELAXED, __HIP_MEMORY_SCOPE_AGENT);
            }
            if (!own) {
                while (!stamp2(x0, x1, knew) && --budget > 0) {
                    x0 = __hip_atomic_load(sbN,       __ATOMIC_RELAXED,
                                           __HIP_MEMORY_SCOPE_AGENT);
                    x1 = __hip_atomic_load(sbN + 256, __ATOMIC_RELAXED,
                                           __HIP_MEMORY_SCOPE_AGENT);
                }
                hTu[0][tid] = (u32)x0;
                hTu[1][tid] = (u32)x1;
            }
            __syncthreads();
            kp1 = knew;
        }
        if (tid < 64) drive[dwofs + (size_t)l * 256] = packh(h0, h1);  // fwd
        dw = dn; gw = gn;
    }
    if (tid < 64) {
        hlast[(size_t)gb * LTC_H + j0]     = h0;
        hlast[(size_t)gb * LTC_H + j0 + 1] = h1;
    }
}

// ---------------------------------------------------------------------------
extern "C" void kernel_launch(void* const* d_in, const int* in_sizes, int n_in,
                              void* d_out, int out_size, void* d_ws, size_t ws_size,
                              hipStream_t stream)
{
    const float* x       = (const float*)d_in[0];
    const float* log_tau = (const float*)d_in[1];
    const float* W_in    = (const float*)d_in[2];
    const float* b_in    = (const float*)d_in[3];
    const float* W_rec   = (const float*)d_in[4];
    const float* W_gate  = (const float*)d_in[5];
    const float* b_gate  = (const float*)d_in[6];
    const float* W_out   = (const float*)d_in[7];
    const float* b_out   = (const float*)d_in[8];

    float* out   = (float*)d_out;                       // (32,1024,512) fp32
    float* hlast = out + (size_t)LTC_B * LTC_L * LTC_H; // (32,512) fp32

    u32* ws    = (u32*)d_ws;                   // 64 MB + 128 KB used
    u32* drive = ws;                           // 8388608 u32 (f16 pairs)
    u32* gatex = ws + 8388608;                 // 8388608 u32
    u64* hbuf  = (u64*)(ws + 16777216);        // 16384 u64 stamped pairs

    const int blocks = (LTC_B * LTC_L / 64) * (LTC_H / 64) / 4;   // 1024

    gemm_a32_c16<<<blocks, 256, 0, stream>>>(x, W_in, LTC_D, b_in, (u16*)drive);
    gemm_a32_c16<<<blocks, 256, 0, stream>>>(x, W_gate, LTC_D + LTC_H, b_gate, (u16*)gatex);
    ltc_scan<<<NG * NP, 256, 0, stream>>>(drive, gatex, W_rec, W_gate, log_tau,
                                          hbuf, hlast);
    gemm_a16_c32<<<blocks, 256, 0, stream>>>((const u16*)drive, W_out, b_out, out);
}